// Round 1
// baseline (407.248 us; speedup 1.0000x reference)
//
#include <hip/hip_runtime.h>

#define NB 8
#define DM 256
#define FD 96

__device__ __forceinline__ float clamp01(float x) { return fminf(fmaxf(x, 0.0f), 1.0f); }

__global__ __launch_bounds__(256, 2) void bio_pinn_kernel(
    const int* __restrict__ bits,
    const float* __restrict__ stim_in,
    const float* __restrict__ Winit,
    const float* __restrict__ lin_w,
    const float* __restrict__ lin_b,
    const int* __restrict__ steps_ptr,
    float* __restrict__ out_emb,
    float* __restrict__ out_h,
    float* __restrict__ out_W,
    int npos)
{
    const int pos = blockIdx.x * blockDim.x + threadIdx.x;
    if (pos >= npos) return;
    const int steps = steps_ptr[0];

    float h[NB][4];   // E,P,G,L per block
    float W[NB][NB];

    // ---- decode bits -> h: pairs (0,1),(2,3),(4,5),(6,7) -> E,P,G,L in {0,1/3,2/3,1}
    const int4* bp = reinterpret_cast<const int4*>(bits + (size_t)pos * 64);
    #pragma unroll
    for (int b = 0; b < NB; ++b) {
        int4 lo = bp[2 * b + 0];
        int4 hi = bp[2 * b + 1];
        h[b][0] = (float)(lo.x * 2 + lo.y) / 3.0f;
        h[b][1] = (float)(lo.z * 2 + lo.w) / 3.0f;
        h[b][2] = (float)(hi.x * 2 + hi.y) / 3.0f;
        h[b][3] = (float)(hi.z * 2 + hi.w) / 3.0f;
    }

    // ---- load W_init, zero diagonal (invariant: diag stays 0 through all steps)
    const float4* wp = reinterpret_cast<const float4*>(Winit + (size_t)pos * 64);
    #pragma unroll
    for (int i = 0; i < NB; ++i) {
        float4 a = wp[2 * i + 0];
        float4 b = wp[2 * i + 1];
        W[i][0] = a.x; W[i][1] = a.y; W[i][2] = a.z; W[i][3] = a.w;
        W[i][4] = b.x; W[i][5] = b.y; W[i][6] = b.z; W[i][7] = b.w;
        W[i][i] = 0.0f;
    }

    const float stim = stim_in[pos];

    // ---- internal steps
    for (int st = 0; st < steps; ++st) {
        // inflow / total_w  -> neigh
        float nb[NB][4];
        #pragma unroll
        for (int i = 0; i < NB; ++i) {
            float s0 = 0.f, s1 = 0.f, s2 = 0.f, s3 = 0.f, tw = 0.f;
            #pragma unroll
            for (int j = 0; j < NB; ++j) {
                float w = W[i][j];
                s0 += w * h[j][0];
                s1 += w * h[j][1];
                s2 += w * h[j][2];
                s3 += w * h[j][3];
                tw += w;
            }
            float inv = 1.0f / (tw + 1e-8f);
            nb[i][0] = s0 * inv; nb[i][1] = s1 * inv;
            nb[i][2] = s2 * inv; nb[i][3] = s3 * inv;
        }
        // h update (uses only own old values + neigh)
        #pragma unroll
        for (int i = 0; i < NB; ++i) {
            float E = h[i][0], P = h[i][1], G = h[i][2], L = h[i][3];
            float En = nb[i][0], Pn = nb[i][1], Gn = nb[i][2], Ln = nb[i][3];
            float E_new = clamp01(E + 0.3f * stim - 0.4f * P - 0.2f * G);
            float P_new = clamp01(P + 0.5f * stim + 0.3f * (Pn - P) - 0.2f * E);
            float G_new = clamp01(G + 0.4f * E * (1.0f - P) + 0.2f * (Gn - G) - 0.3f * P);
            float good  = 0.5f * En + 0.5f * Gn;
            float L_new = clamp01(L + 0.4f * good + 0.3f * (Ln - L) - 0.3f * P);
            h[i][0] = E_new; h[i][1] = P_new; h[i][2] = G_new; h[i][3] = L_new;
        }
        // W update: symmetric-pair distances, asymmetric W entries
        #pragma unroll
        for (int i = 0; i < NB; ++i) {
            #pragma unroll
            for (int j = i + 1; j < NB; ++j) {
                float d0 = h[i][0] - h[j][0];
                float d1 = h[i][1] - h[j][1];
                float d2 = h[i][2] - h[j][2];
                float d3 = h[i][3] - h[j][3];
                float q = d0 * d0 + d1 * d1 + d2 * d2 + d3 * d3;
                float dist = (q > 0.0f) ? sqrtf(q) : 0.0f;
                float inc = 0.1f * (0.5f * (h[i][3] + h[j][3])) * dist;
                W[i][j] = clamp01(W[i][j] + inc - 0.05f * W[i][j]);
                W[j][i] = clamp01(W[j][i] + inc - 0.05f * W[j][i]);
            }
        }
    }

    // ---- write h, W outputs (float4, per-lane contiguous)
    float4* hop = reinterpret_cast<float4*>(out_h + (size_t)pos * 32);
    #pragma unroll
    for (int i = 0; i < NB; ++i)
        hop[i] = make_float4(h[i][0], h[i][1], h[i][2], h[i][3]);

    float4* wop = reinterpret_cast<float4*>(out_W + (size_t)pos * 64);
    #pragma unroll
    for (int i = 0; i < NB; ++i) {
        wop[2 * i + 0] = make_float4(W[i][0], W[i][1], W[i][2], W[i][3]);
        wop[2 * i + 1] = make_float4(W[i][4], W[i][5], W[i][6], W[i][7]);
    }

    // ---- einsum: emb[d] = lin_b[d] + sum_f phys[f] * lin_w[d][f]
    // phys[0..31]  = h (block-major), phys[32..95] = W (row-major)
    // lin_w accesses are wave-uniform -> expect s_load + v_fmac (SGPR operand)
    float* ep = out_emb + (size_t)pos * DM;
    for (int d0 = 0; d0 < DM; d0 += 8) {
        float acc[8];
        #pragma unroll
        for (int t = 0; t < 8; ++t) {
            const float* lw = lin_w + (size_t)(d0 + t) * FD;
            float a = lin_b[d0 + t];
            #pragma unroll
            for (int b = 0; b < NB; ++b) {
                a += h[b][0] * lw[b * 4 + 0];
                a += h[b][1] * lw[b * 4 + 1];
                a += h[b][2] * lw[b * 4 + 2];
                a += h[b][3] * lw[b * 4 + 3];
            }
            #pragma unroll
            for (int i = 0; i < NB; ++i) {
                #pragma unroll
                for (int j = 0; j < NB; ++j)
                    a += W[i][j] * lw[32 + i * 8 + j];
            }
            acc[t] = a;
        }
        float4* op = reinterpret_cast<float4*>(ep + d0);
        op[0] = make_float4(acc[0], acc[1], acc[2], acc[3]);
        op[1] = make_float4(acc[4], acc[5], acc[6], acc[7]);
    }
}

extern "C" void kernel_launch(void* const* d_in, const int* in_sizes, int n_in,
                              void* d_out, int out_size, void* d_ws, size_t ws_size,
                              hipStream_t stream) {
    const int*   bits  = (const int*)d_in[0];
    const float* stim  = (const float*)d_in[1];
    const float* Winit = (const float*)d_in[2];
    const float* lin_w = (const float*)d_in[3];
    const float* lin_b = (const float*)d_in[4];
    const int*   steps = (const int*)d_in[5];

    const int npos = in_sizes[1];  // B*S = 131072 (macro_stimulus element count)

    float* out_emb = (float*)d_out;
    float* out_h   = out_emb + (size_t)npos * DM;   // after [npos,256]
    float* out_W   = out_h + (size_t)npos * 32;     // after [npos,8,4]

    const int threads = 256;
    const int blocks = (npos + threads - 1) / threads;
    hipLaunchKernelGGL(bio_pinn_kernel, dim3(blocks), dim3(threads), 0, stream,
                       bits, stim, Winit, lin_w, lin_b, steps,
                       out_emb, out_h, out_W, npos);
}